// Round 8
// baseline (101.631 us; speedup 1.0000x reference)
//
#include <hip/hip_runtime.h>
#include <hip/hip_bf16.h>
#include <stdint.h>

#define Bsz 128
#define Tn  512
#define In  700
#define On  128
#define Mn  (Bsz * Tn)   // 65536
#define KP  704          // K padded to multiple of 32
#define NSEG 16
#define LSEG 32          // Tn / NSEG
#define BO   (Bsz * On)  // 16384 chains
#define NKT  22          // K tiles of 32

using bf16x8 = __attribute__((ext_vector_type(8))) short;
using f32x4  = __attribute__((ext_vector_type(4))) float;

__device__ __forceinline__ uint32_t f2bf(float f) {
  union { float f; uint32_t u; } v; v.f = f;
  return (v.u + 0x7fffu + ((v.u >> 16) & 1u)) >> 16;   // RNE
}
// round to bf16, return as exact fp32 (low mantissa zeroed)
__device__ __forceinline__ float bf16exact(float x) {
  union { float f; uint32_t u; } v; v.f = x;
  v.u = (v.u + 0x7fffu + ((v.u >> 16) & 1u)) & 0xFFFF0000u;
  return v.f;
}
__device__ __forceinline__ float bitsf(uint32_t u) {
  union { float f; uint32_t x; } v; v.x = u; return v.f;
}
__device__ __forceinline__ uint32_t topbits(float x) {
  union { float f; uint32_t u; } v; v.f = x; return v.u;
}

// pairwise f32->bf16 via v_cvt_pk_bf16_f32 (compiler-generated, RNE)
__device__ __forceinline__ bf16x8 cvt8(float4 f0, float4 f1) {
  union { __hip_bfloat162 h2[4]; bf16x8 v; } u;
  u.h2[0] = __float22bfloat162_rn(make_float2(f0.x, f0.y));
  u.h2[1] = __float22bfloat162_rn(make_float2(f0.z, f0.w));
  u.h2[2] = __float22bfloat162_rn(make_float2(f1.x, f1.y));
  u.h2[3] = __float22bfloat162_rn(make_float2(f1.z, f1.w));
  return u.v;
}

// ---- prep: w (700x128 f32, k-major) -> w_t (128 x 704 bf16, zero-padded K) ----
__global__ void prep_wt(const float* __restrict__ w, ushort* __restrict__ w_t) {
  int idx = blockIdx.x * 256 + threadIdx.x;
  if (idx >= On * KP) return;
  int col = idx / KP, k = idx - col * KP;
  float v = (k < In) ? w[(size_t)k * On + col] : 0.0f;
  w_t[(size_t)col * KP + k] = (ushort)f2bf(v);
}

// ======================= GEMM, barrier-free K-loop =======================
// Wave-tile = 32 rows x 128 cols: A rows are wave-exclusive -> stream A
// global->reg (fp32->bf16 in-reg), B from L2-resident Wt. No LDS, no barriers
// in the K-loop; explicit 2-stage register pipeline. LDS (sc) only for the
// epilogue: phase-A endpoint scan + coalesced h write.
template <bool HB16>
__global__ __launch_bounds__(256, 2) void gemm_h2(
    const float* __restrict__ A,    // 65536 x 700 f32
    const ushort* __restrict__ Wt,  // 128 x 704 bf16
    float* __restrict__ Hf,         // fp32 h out (syn region)  [!HB16]
    ushort* __restrict__ Hb,        // bf16 h out (d_ws)        [HB16]
    float2* __restrict__ ep,        // [NSEG][BO] endpoints (may be null)
    const float* __restrict__ alpha, const float* __restrict__ beta)
{
  __shared__ float sc[128 * 132];   // 66 KB (pad 132)

  const int tid  = threadIdx.x;
  const int bm   = blockIdx.x;      // 512 blocks: batch b = bm>>2, quarter = bm&3
  const int lane = tid & 63;
  const int w    = tid >> 6;        // 4 waves, each 32 rows x 128 cols
  const int l16  = lane & 15, lkb = lane >> 4;

  const int   o_ep = tid & 127;
  const float a_ep = alpha[o_ep];
  const float b_ep = beta[o_ep];

  // per-lane row pointers (mt=0 rows, mt=1 rows) and B pointer
  const float*  ap0 = A + (size_t)(bm * 128 + w * 32 + l16) * In + lkb * 8;
  const float*  ap1 = ap0 + (size_t)16 * In;
  const ushort* wp  = Wt + (size_t)l16 * KP + lkb * 8;

  f32x4 acc[2][8];
#pragma unroll
  for (int m = 0; m < 2; ++m)
#pragma unroll
    for (int n = 0; n < 8; ++n) acc[m][n] = (f32x4){0.f, 0.f, 0.f, 0.f};

  // register tile: A raw fp32 (4x float4) + B (8x bf16x8)
  struct Tile { float4 a00, a01, a10, a11; bf16x8 b[8]; };
  auto loadT = [&](int kt, Tile& T) {
    const int k0 = kt * 32;
    const int gk = k0;                         // lane offset lkb*8 already in ptr
    // clamp second half so the last tile stays in-bounds (values x Wt-zeros)
    const int d2 = (k0 + lkb * 8 + 4 <= In - 4) ? 4 : (In - 4 - (k0 + lkb * 8));
    T.a00 = *(const float4*)(ap0 + gk);
    T.a01 = *(const float4*)(ap0 + gk + d2);
    T.a10 = *(const float4*)(ap1 + gk);
    T.a11 = *(const float4*)(ap1 + gk + d2);
#pragma unroll
    for (int n = 0; n < 8; ++n)
      T.b[n] = *(const bf16x8*)(wp + (size_t)n * 16 * KP + k0);
  };
  auto compute = [&](const Tile& T) {
    bf16x8 af0 = cvt8(T.a00, T.a01);
    bf16x8 af1 = cvt8(T.a10, T.a11);
#pragma unroll
    for (int n = 0; n < 8; ++n) {
      acc[0][n] = __builtin_amdgcn_mfma_f32_16x16x32_bf16(af0, T.b[n], acc[0][n], 0, 0, 0);
      acc[1][n] = __builtin_amdgcn_mfma_f32_16x16x32_bf16(af1, T.b[n], acc[1][n], 0, 0, 0);
    }
  };

  Tile R0, R1;
  loadT(0, R0);
#pragma unroll 1
  for (int kt = 0; kt < NKT - 2; kt += 2) {   // 0..19
    loadT(kt + 1, R1);
    compute(R0);
    loadT(kt + 2, R0);
    compute(R1);
  }
  loadT(NKT - 1, R1);
  compute(R0);
  compute(R1);

  // ---- epilogue: acc -> LDS sc (t-major, pad 132); HB16 rounds bf16-exact ----
  // D frag: col = l16 (+n*16), row = lkb*4 + r (+mt*16) within the wave's 32 rows
#pragma unroll
  for (int m = 0; m < 2; ++m)
#pragma unroll
    for (int n = 0; n < 8; ++n) {
      const int col = n * 16 + l16;
#pragma unroll
      for (int r = 0; r < 4; ++r) {
        const int row = w * 32 + m * 16 + lkb * 4 + r;
        float v = acc[m][n][r];
        if constexpr (HB16) v = bf16exact(v);
        sc[row * 132 + col] = v;
      }
    }
  __syncthreads();

  // coalesced h write from LDS
  if constexpr (HB16) {
#pragma unroll
    for (int i2 = 0; i2 < 8; ++i2) {
      const int q = i2 * 256 + tid;
      const int row = q >> 4, v8 = q & 15;
      const float4 f0 = *(const float4*)&sc[row * 132 + v8 * 8];
      const float4 f1 = *(const float4*)&sc[row * 132 + v8 * 8 + 4];
      uint4 pk;
      pk.x = (topbits(f0.x) >> 16) | (topbits(f0.y) & 0xFFFF0000u);
      pk.y = (topbits(f0.z) >> 16) | (topbits(f0.w) & 0xFFFF0000u);
      pk.z = (topbits(f1.x) >> 16) | (topbits(f1.y) & 0xFFFF0000u);
      pk.w = (topbits(f1.z) >> 16) | (topbits(f1.w) & 0xFFFF0000u);
      *(uint4*)&Hb[(size_t)(bm * 128 + row) * 128 + v8 * 8] = pk;
    }
  } else {
    const size_t hbase = (size_t)bm * 128 * 128;
#pragma unroll
    for (int i2 = 0; i2 < 16; ++i2) {
      const int q = i2 * 256 + tid;
      const int row = q >> 5, v = q & 31;
      *(float4*)&Hf[hbase + row * 128 + v * 4] =
          *(const float4*)&sc[row * 132 + v * 4];
    }
  }

  // fused phase A: per-segment local scan from zero (4 segs x 128 cols)
  if (ep) {
    const float a = a_ep, bt = b_ep, omb = 1.0f - b_ep;
    const int b = bm >> 2, seg0 = (bm & 3) * 4;
#pragma unroll
    for (int cc = 0; cc < 2; ++cc) {
      const int sl = (tid >> 7) + cc * 2;
      float S = 0.f, M = 0.f;
      const float* base = &sc[(sl * 32) * 132 + o_ep];
#pragma unroll
      for (int t = 0; t < 32; ++t) {
        const float x = base[t * 132];
        M = fmaf(bt, M, omb * S);   // uses OLD S
        S = fmaf(a, S, x);
      }
      ep[(size_t)(seg0 + sl) * BO + b * On + o_ep] = make_float2(S, M);
    }
  }
}

// ---- Phase B+C, bf16-h, 2 o's per thread (512 blocks = 2/CU) ----
__global__ __launch_bounds__(256) void scan_segb(
    float* __restrict__ syn, float* __restrict__ mem,
    const ushort* __restrict__ Hb, const float2* __restrict__ ep,
    const float* __restrict__ alpha, const float* __restrict__ beta)
{
  const int cid = blockIdx.x * 256 + threadIdx.x;   // 128*16*64 = 131072
  const int o2  = cid & 63;
  const int seg = (cid >> 6) & (NSEG - 1);
  const int b   = cid >> 10;
  const int o   = 2 * o2;

  const float2 al2 = *(const float2*)&alpha[o];
  const float2 be2 = *(const float2*)&beta[o];
  const float a0 = al2.x, a1 = al2.y, b0 = be2.x, b1 = be2.y;
  const float ob0 = 1.f - b0, ob1 = 1.f - b1;

  float aL0 = 1.f, bL0 = 1.f, cL0 = 0.f, aL1 = 1.f, bL1 = 1.f, cL1 = 0.f;
#pragma unroll
  for (int i = 0; i < LSEG; ++i) {
    cL0 = fmaf(b0, cL0, ob0 * aL0); aL0 *= a0; bL0 *= b0;
    cL1 = fmaf(b1, cL1, ob1 * aL1); aL1 *= a1; bL1 *= b1;
  }

  float S0 = 0.f, M0 = 0.f, S1 = 0.f, M1 = 0.f;
  for (int j = 0; j < seg; ++j) {
    const float4 E = *(const float4*)&ep[(size_t)j * BO + b * On + o];
    const float nS0 = fmaf(aL0, S0, E.x);
    M0 = fmaf(bL0, M0, fmaf(cL0, S0, E.y));   // uses OLD S
    S0 = nS0;
    const float nS1 = fmaf(aL1, S1, E.z);
    M1 = fmaf(bL1, M1, fmaf(cL1, S1, E.w));
    S1 = nS1;
  }

  const ushort* hp = Hb + ((size_t)b * Tn + seg * LSEG) * On + o;
  float* sp = syn + ((size_t)b * Tn + seg * LSEG) * On + o;
  float* mp = mem + ((size_t)b * Tn + seg * LSEG) * On + o;
  uint32_t buf[8];
#pragma unroll
  for (int d = 0; d < 8; ++d) buf[d] = *(const uint32_t*)&hp[d * On];
  for (int tb = 0; tb < LSEG; tb += 8) {
#pragma unroll
    for (int d = 0; d < 8; ++d) {
      const int t = tb + d;
      const uint32_t u = buf[d];
      if (t + 8 < LSEG) buf[d] = *(const uint32_t*)&hp[(t + 8) * On];
      *(float2*)&sp[(size_t)t * On] = make_float2(S0, S1);
      *(float2*)&mp[(size_t)t * On] = make_float2(M0, M1);
      const float x0 = bitsf(u << 16);
      const float x1 = bitsf(u & 0xFFFF0000u);
      M0 = fmaf(b0, M0, ob0 * S0); S0 = fmaf(a0, S0, x0);   // M uses OLD S
      M1 = fmaf(b1, M1, ob1 * S1); S1 = fmaf(a1, S1, x1);
    }
  }
}

// ---- Phase B+C, fp32-h fallback (h in syn region, in-place) ----
__global__ __launch_bounds__(256) void scan_seg(
    float* __restrict__ syn, float* __restrict__ mem, const float2* __restrict__ ep,
    const float* __restrict__ alpha, const float* __restrict__ beta)
{
  const int cid = blockIdx.x * 256 + threadIdx.x;
  const int o2  = cid & 63;
  const int seg = (cid >> 6) & (NSEG - 1);
  const int b   = cid >> 10;
  const int o   = 2 * o2;

  const float2 al2 = *(const float2*)&alpha[o];
  const float2 be2 = *(const float2*)&beta[o];
  const float a0 = al2.x, a1 = al2.y, b0 = be2.x, b1 = be2.y;
  const float ob0 = 1.f - b0, ob1 = 1.f - b1;

  float aL0 = 1.f, bL0 = 1.f, cL0 = 0.f, aL1 = 1.f, bL1 = 1.f, cL1 = 0.f;
#pragma unroll
  for (int i = 0; i < LSEG; ++i) {
    cL0 = fmaf(b0, cL0, ob0 * aL0); aL0 *= a0; bL0 *= b0;
    cL1 = fmaf(b1, cL1, ob1 * aL1); aL1 *= a1; bL1 *= b1;
  }

  float S0 = 0.f, M0 = 0.f, S1 = 0.f, M1 = 0.f;
  for (int j = 0; j < seg; ++j) {
    const float4 E = *(const float4*)&ep[(size_t)j * BO + b * On + o];
    const float nS0 = fmaf(aL0, S0, E.x);
    M0 = fmaf(bL0, M0, fmaf(cL0, S0, E.y));
    S0 = nS0;
    const float nS1 = fmaf(aL1, S1, E.z);
    M1 = fmaf(bL1, M1, fmaf(cL1, S1, E.w));
    S1 = nS1;
  }

  float* hp = syn + ((size_t)b * Tn + seg * LSEG) * On + o;
  float* mp = mem + ((size_t)b * Tn + seg * LSEG) * On + o;
  float2 buf[8];
#pragma unroll
  for (int d = 0; d < 8; ++d) buf[d] = *(const float2*)&hp[d * On];
  for (int tb = 0; tb < LSEG; tb += 8) {
#pragma unroll
    for (int d = 0; d < 8; ++d) {
      const int t = tb + d;
      const float2 x = buf[d];
      if (t + 8 < LSEG) buf[d] = *(const float2*)&hp[(t + 8) * On];
      *(float2*)&hp[(size_t)t * On] = make_float2(S0, S1);
      *(float2*)&mp[(size_t)t * On] = make_float2(M0, M1);
      M0 = fmaf(b0, M0, ob0 * S0); S0 = fmaf(a0, S0, x.x);
      M1 = fmaf(b1, M1, ob1 * S1); S1 = fmaf(a1, S1, x.y);
    }
  }
}

// ---- fallback single-pass scan (used only if ws_size is tiny) ----
__global__ __launch_bounds__(64) void scan_k(
    float* __restrict__ syn, float* __restrict__ mem,
    const float* __restrict__ alpha, const float* __restrict__ beta)
{
  const int b = blockIdx.x >> 1;
  const int o = ((blockIdx.x & 1) << 6) + threadIdx.x;
  const float a = alpha[o], bt = beta[o], omb = 1.0f - bt;
  float* hp = syn + (size_t)b * Tn * On + o;
  float* mp = mem + (size_t)b * Tn * On + o;
  float S = 0.f, M = 0.f;
  float buf[8];
#pragma unroll
  for (int d = 0; d < 8; ++d) buf[d] = hp[d * On];
  for (int tb = 0; tb < Tn; tb += 8) {
#pragma unroll
    for (int d = 0; d < 8; ++d) {
      const int t = tb + d;
      const float h_t = buf[d];
      if (t + 8 < Tn) buf[d] = hp[(t + 8) * On];
      hp[t * On] = S;
      mp[t * On] = M;
      const float nS = fmaf(a, S, h_t);
      M = fmaf(bt, M, omb * S);
      S = nS;
    }
  }
}

extern "C" void kernel_launch(void* const* d_in, const int* in_sizes, int n_in,
                              void* d_out, int out_size, void* d_ws, size_t ws_size,
                              hipStream_t stream) {
  const float* inputs = (const float*)d_in[0];   // (128,512,700)
  const float* w      = (const float*)d_in[1];   // (700,128)
  const float* alpha  = (const float*)d_in[2];   // (1,128)
  const float* beta   = (const float*)d_in[3];   // (1,128)

  float* syn = (float*)d_out;                    // first 8M floats
  float* mem = syn + (size_t)Bsz * Tn * On;      // next 8M floats
  ushort* w_t = (ushort*)mem;                    // 180 KB temp in mem region,
                                                 // consumed by gemm before scan writes

  const size_t ep_bytes = (size_t)NSEG * BO * sizeof(float2);  // 2 MB
  const size_t hb_bytes = (size_t)Mn * On * sizeof(ushort);    // 16.78 MB

  prep_wt<<<(On * KP + 255) / 256, 256, 0, stream>>>(w, w_t);

  if (ws_size >= ep_bytes + hb_bytes) {
    float2* ep = (float2*)d_ws;
    ushort* hb = (ushort*)((char*)d_ws + ep_bytes);
    gemm_h2<true><<<Mn / 128, 256, 0, stream>>>(inputs, w_t, nullptr, hb, ep, alpha, beta);
    scan_segb<<<(Bsz * NSEG * On / 2) / 256, 256, 0, stream>>>(syn, mem, hb, ep, alpha, beta);
  } else if (ws_size >= ep_bytes) {
    float2* ep = (float2*)d_ws;
    gemm_h2<false><<<Mn / 128, 256, 0, stream>>>(inputs, w_t, syn, nullptr, ep, alpha, beta);
    scan_seg<<<(Bsz * NSEG * On / 2) / 256, 256, 0, stream>>>(syn, mem, ep, alpha, beta);
  } else {
    gemm_h2<false><<<Mn / 128, 256, 0, stream>>>(inputs, w_t, syn, nullptr, nullptr, alpha, beta);
    scan_k<<<Bsz * 2, 64, 0, stream>>>(syn, mem, alpha, beta);
  }
}

// Round 9
// 66.014 us; speedup vs baseline: 1.5395x; 1.5395x over previous
//
#include <hip/hip_runtime.h>
#include <hip/hip_bf16.h>
#include <stdint.h>

#define Bsz 128
#define Tn  512
#define In  700
#define On  128
#define Mn  (Bsz * Tn)   // 65536
#define KP  704          // K padded to multiple of 32
#define NSEG 16
#define LSEG 32          // Tn / NSEG
#define BO   (Bsz * On)  // 16384 chains
#define NKT  22          // K tiles of 32
#define SCP  136         // ushort sc row pitch (272B, 16B-aligned)

using bf16x8 = __attribute__((ext_vector_type(8))) short;
using f32x4  = __attribute__((ext_vector_type(4))) float;

#define WAITVM(N) asm volatile("s_waitcnt vmcnt(" #N ")" ::: "memory")

__device__ __forceinline__ uint32_t f2bf(float f) {
  union { float f; uint32_t u; } v; v.f = f;
  return (v.u + 0x7fffu + ((v.u >> 16) & 1u)) >> 16;   // RNE
}
__device__ __forceinline__ float bf2f(ushort u) {
  union { float f; uint32_t x; } v; v.x = ((uint32_t)u) << 16;
  return v.f;
}
__device__ __forceinline__ float bitsf(uint32_t u) {
  union { float f; uint32_t x; } v; v.x = u; return v.f;
}

// pairwise f32->bf16 via v_cvt_pk_bf16_f32 (compiler-generated, RNE)
__device__ __forceinline__ bf16x8 cvt8(float4 f0, float4 f1) {
  union { __hip_bfloat162 h2[4]; bf16x8 v; } u;
  u.h2[0] = __float22bfloat162_rn(make_float2(f0.x, f0.y));
  u.h2[1] = __float22bfloat162_rn(make_float2(f0.z, f0.w));
  u.h2[2] = __float22bfloat162_rn(make_float2(f1.x, f1.y));
  u.h2[3] = __float22bfloat162_rn(make_float2(f1.z, f1.w));
  return u.v;
}

// async global->LDS, 16B per lane; LDS dest = wave-uniform base + lane*16
__device__ __forceinline__ void gload16(const void* g, void* l) {
  __builtin_amdgcn_global_load_lds(
      (__attribute__((address_space(1))) void*)g,
      (__attribute__((address_space(3))) void*)l, 16, 0, 0);
}

// ---- prep: w (700x128 f32, k-major) -> w_t (128 x 704 bf16, zero-padded K) ----
__global__ void prep_wt(const float* __restrict__ w, ushort* __restrict__ w_t) {
  int idx = blockIdx.x * 256 + threadIdx.x;
  if (idx >= On * KP) return;
  int col = idx / KP, k = idx - col * KP;
  float v = (k < In) ? w[(size_t)k * On + col] : 0.0f;
  w_t[(size_t)col * KP + k] = (ushort)f2bf(v);
}

// =================== GEMM, bf16-h primary (48 KB LDS -> 3 blocks/CU) ===================
// 2-deep global_load_lds pipeline, counted vmcnt (6 steady, 0 only at the end).
union SMU16 {
  struct {
    uint32_t A[2][4096];   // 32 KB: fp32 tile 128 rows x 8 slots x 16B, src-swizzled
    uint32_t B[2][2048];   // 16 KB: bf16 tile 128 cols x 4 slots x 16B, src-swizzled
  } db;                    // 48 KB staging
  ushort sc[128 * SCP];    // 34.8 KB h buffer (bf16 bits, t-major)
};

__global__ __launch_bounds__(256, 3) void gemm_hb(
    const float* __restrict__ A,    // 65536 x 700 f32
    const ushort* __restrict__ Wt,  // 128 x 704 bf16
    ushort* __restrict__ Hb,        // bf16 h out (d_ws)
    float2* __restrict__ ep,        // [NSEG][BO] endpoints
    const float* __restrict__ alpha, const float* __restrict__ beta)
{
  __shared__ __align__(16) SMU16 sm;

  const int tid  = threadIdx.x;
  const int bm   = blockIdx.x;        // 512 blocks: batch b = bm>>2, quarter = bm&3
  const int lane = tid & 63;
  const int wid  = tid >> 6;          // 4 waves, 2x2 wave grid (64x64 each)
  const int wm   = wid >> 1, wn = wid & 1;
  const int l16  = lane & 15, lkb = lane >> 4;

  // alpha/beta for phase A; drain so the counted vmcnt pipeline stays exact
  const int   o_ep = tid & 127;
  const float a_ep = alpha[o_ep];
  const float b_ep = beta[o_ep];
  WAITVM(0);
  __builtin_amdgcn_sched_barrier(0);

  f32x4 acc[4][4];
#pragma unroll
  for (int i = 0; i < 4; ++i)
#pragma unroll
    for (int n = 0; n < 4; ++n) acc[i][n] = (f32x4){0.f, 0.f, 0.f, 0.f};

  auto stage = [&](int bi, int kt) {   // 6 loads per wave
    const int k0 = kt * 32;
#pragma unroll
    for (int is = 0; is < 4; ++is) {
      const int q   = is * 256 + wid * 64 + lane;
      const int row = q >> 3, sl = q & 7;
      int gk = k0 + ((sl ^ (row & 7)) << 2);
      if (gk >= In) gk = k0;                        // clamp; Wt zero at k>=700
      gload16(A + (size_t)(bm * 128 + row) * In + gk,
              &sm.db.A[bi][is * 1024 + wid * 256]);
    }
#pragma unroll
    for (int is = 0; is < 2; ++is) {
      const int q   = is * 256 + wid * 64 + lane;
      const int col = q >> 2, sl = q & 3;
      const int ks  = sl ^ ((col >> 1) & 3);
      gload16(Wt + (size_t)col * KP + k0 + ks * 8,
              &sm.db.B[bi][is * 1024 + wid * 256]);
    }
  };

  auto tile = [&](int kt, int cur) {
    __builtin_amdgcn_s_barrier();
    const float4* Af = (const float4*)sm.db.A[cur];
    const bf16x8* Bf = (const bf16x8*)sm.db.B[cur];
    bf16x8 af[4], bfr[4];
#pragma unroll
    for (int i = 0; i < 4; ++i) {
      const int row = wm * 64 + i * 16 + l16;
      const int s0  = (lkb * 2) ^ (row & 7);
      const int s1  = (lkb * 2 + 1) ^ (row & 7);
      af[i] = cvt8(Af[row * 8 + s0], Af[row * 8 + s1]);
    }
#pragma unroll
    for (int n = 0; n < 4; ++n) {
      const int col = wn * 64 + n * 16 + l16;
      bfr[n] = Bf[col * 4 + (lkb ^ ((col >> 1) & 3))];
    }
    asm volatile("s_waitcnt lgkmcnt(0)" ::: "memory");
    __builtin_amdgcn_s_barrier();
    if (kt + 2 < NKT) stage(cur, kt + 2);   // overwrite just-consumed buffer
#pragma unroll
    for (int i = 0; i < 4; ++i)
#pragma unroll
      for (int n = 0; n < 4; ++n)
        acc[i][n] = __builtin_amdgcn_mfma_f32_16x16x32_bf16(af[i], bfr[n], acc[i][n], 0, 0, 0);
  };

  stage(0, 0); stage(1, 1);               // 12 loads/wave in flight
  for (int kt = 0; kt < NKT - 1; ++kt) {  // kt = 0..20
    WAITVM(6);                            // tile kt landed; kt+1 stays in flight
    tile(kt, kt & 1);
  }
  WAITVM(0);
  tile(NKT - 1, (NKT - 1) & 1);

  // ---- epilogue: acc -> bf16 bits in LDS sc (t-major, pitch 136) ----
#pragma unroll
  for (int i = 0; i < 4; ++i)
#pragma unroll
    for (int n = 0; n < 4; ++n) {
      const int col = wn * 64 + n * 16 + l16;
#pragma unroll
      for (int r = 0; r < 4; ++r) {
        const int row = wm * 64 + i * 16 + lkb * 4 + r;
        sm.sc[row * SCP + col] = (ushort)f2bf(acc[i][n][r]);
      }
    }
  __syncthreads();

  // coalesced h write from LDS: 16B (8 bf16) per thread per pass
#pragma unroll
  for (int i2 = 0; i2 < 8; ++i2) {
    const int q = i2 * 256 + tid;
    const int row = q >> 4, v8 = q & 15;
    *(uint4*)&Hb[(size_t)(bm * 128 + row) * 128 + v8 * 8] =
        *(const uint4*)&sm.sc[row * SCP + v8 * 8];
  }

  // fused phase A: per-segment local scan from zero (4 segs x 128 cols)
  {
    const float a = a_ep, bt = b_ep, omb = 1.0f - b_ep;
    const int b = bm >> 2, seg0 = (bm & 3) * 4;
#pragma unroll
    for (int cc = 0; cc < 2; ++cc) {
      const int sl = (tid >> 7) + cc * 2;
      float S = 0.f, M = 0.f;
      const ushort* base = &sm.sc[(sl * 32) * SCP + o_ep];
#pragma unroll
      for (int t = 0; t < 32; ++t) {
        const float x = bf2f(base[t * SCP]);
        M = fmaf(bt, M, omb * S);   // uses OLD S
        S = fmaf(a, S, x);
      }
      ep[(size_t)(seg0 + sl) * BO + b * On + o_ep] = make_float2(S, M);
    }
  }
}

// =================== fp32-h fallback GEMM (round-6 proven, 3-deep) ===================
union SMU {
  struct {
    uint32_t A[3][4096];
    uint32_t B[3][2048];
  } db;                    // 72 KB
  float sc[128 * 132];     // 66 KB
};

__global__ __launch_bounds__(256, 2) void gemm_h(
    const float* __restrict__ A, const ushort* __restrict__ Wt,
    float* __restrict__ Hf, float2* __restrict__ ep,
    const float* __restrict__ alpha, const float* __restrict__ beta)
{
  __shared__ __align__(16) SMU sm;
  const int tid  = threadIdx.x;
  const int bm   = blockIdx.x;
  const int lane = tid & 63;
  const int wid  = tid >> 6;
  const int wm   = wid >> 1, wn = wid & 1;
  const int l16  = lane & 15, lkb = lane >> 4;

  const int   o_ep = tid & 127;
  const float a_ep = alpha[o_ep];
  const float b_ep = beta[o_ep];
  WAITVM(0);
  __builtin_amdgcn_sched_barrier(0);

  f32x4 acc[4][4];
#pragma unroll
  for (int i = 0; i < 4; ++i)
#pragma unroll
    for (int n = 0; n < 4; ++n) acc[i][n] = (f32x4){0.f, 0.f, 0.f, 0.f};

  auto stage = [&](int bi, int kt) {
    const int k0 = kt * 32;
#pragma unroll
    for (int is = 0; is < 4; ++is) {
      const int q   = is * 256 + wid * 64 + lane;
      const int row = q >> 3, sl = q & 7;
      int gk = k0 + ((sl ^ (row & 7)) << 2);
      if (gk >= In) gk = k0;
      gload16(A + (size_t)(bm * 128 + row) * In + gk,
              &sm.db.A[bi][is * 1024 + wid * 256]);
    }
#pragma unroll
    for (int is = 0; is < 2; ++is) {
      const int q   = is * 256 + wid * 64 + lane;
      const int col = q >> 2, sl = q & 3;
      const int ks  = sl ^ ((col >> 1) & 3);
      gload16(Wt + (size_t)col * KP + k0 + ks * 8,
              &sm.db.B[bi][is * 1024 + wid * 256]);
    }
  };

  auto tile = [&](int kt, int cur) {
    __builtin_amdgcn_s_barrier();
    const float4* Af = (const float4*)sm.db.A[cur];
    const bf16x8* Bf = (const bf16x8*)sm.db.B[cur];
    bf16x8 af[4], bfr[4];
#pragma unroll
    for (int i = 0; i < 4; ++i) {
      const int row = wm * 64 + i * 16 + l16;
      const int s0  = (lkb * 2) ^ (row & 7);
      const int s1  = (lkb * 2 + 1) ^ (row & 7);
      af[i] = cvt8(Af[row * 8 + s0], Af[row * 8 + s1]);
    }
#pragma unroll
    for (int n = 0; n < 4; ++n) {
      const int col = wn * 64 + n * 16 + l16;
      bfr[n] = Bf[col * 4 + (lkb ^ ((col >> 1) & 3))];
    }
    asm volatile("s_waitcnt lgkmcnt(0)" ::: "memory");
    __builtin_amdgcn_s_barrier();
    if (kt + 3 < NKT) stage(cur, kt + 3);
#pragma unroll
    for (int i = 0; i < 4; ++i)
#pragma unroll
      for (int n = 0; n < 4; ++n)
        acc[i][n] = __builtin_amdgcn_mfma_f32_16x16x32_bf16(af[i], bfr[n], acc[i][n], 0, 0, 0);
  };

  stage(0, 0); stage(1, 1); stage(2, 2);
  {
    int cur = 0;
    for (int kt = 0; kt < NKT - 2; ++kt) {
      WAITVM(12);
      tile(kt, cur);
      cur = (cur == 2) ? 0 : cur + 1;
    }
    WAITVM(6);  tile(NKT - 2, (NKT - 2) % 3);
    WAITVM(0);  tile(NKT - 1, (NKT - 1) % 3);
  }

#pragma unroll
  for (int i = 0; i < 4; ++i)
#pragma unroll
    for (int n = 0; n < 4; ++n) {
      const int col = wn * 64 + n * 16 + l16;
#pragma unroll
      for (int r = 0; r < 4; ++r) {
        const int row = wm * 64 + i * 16 + lkb * 4 + r;
        sm.sc[row * 132 + col] = acc[i][n][r];
      }
    }
  __syncthreads();

  const size_t hbase = (size_t)bm * 128 * 128;
#pragma unroll
  for (int i2 = 0; i2 < 16; ++i2) {
    const int q = i2 * 256 + tid;
    const int row = q >> 5, v = q & 31;
    *(float4*)&Hf[hbase + row * 128 + v * 4] =
        *(const float4*)&sm.sc[row * 132 + v * 4];
  }

  if (ep) {
    const float a = a_ep, bt = b_ep, omb = 1.0f - b_ep;
    const int b = bm >> 2, seg0 = (bm & 3) * 4;
#pragma unroll
    for (int cc = 0; cc < 2; ++cc) {
      const int sl = (tid >> 7) + cc * 2;
      float S = 0.f, M = 0.f;
      const float* base = &sm.sc[(sl * 32) * 132 + o_ep];
#pragma unroll
      for (int t = 0; t < 32; ++t) {
        const float x = base[t * 132];
        M = fmaf(bt, M, omb * S);
        S = fmaf(a, S, x);
      }
      ep[(size_t)(seg0 + sl) * BO + b * On + o_ep] = make_float2(S, M);
    }
  }
}

// ---- Phase B+C, bf16-h, 2 o's per thread (512 blocks) ----
__global__ __launch_bounds__(256) void scan_segb(
    float* __restrict__ syn, float* __restrict__ mem,
    const ushort* __restrict__ Hb, const float2* __restrict__ ep,
    const float* __restrict__ alpha, const float* __restrict__ beta)
{
  const int cid = blockIdx.x * 256 + threadIdx.x;   // 128*16*64 = 131072
  const int o2  = cid & 63;
  const int seg = (cid >> 6) & (NSEG - 1);
  const int b   = cid >> 10;
  const int o   = 2 * o2;

  const float2 al2 = *(const float2*)&alpha[o];
  const float2 be2 = *(const float2*)&beta[o];
  const float a0 = al2.x, a1 = al2.y, b0 = be2.x, b1 = be2.y;
  const float ob0 = 1.f - b0, ob1 = 1.f - b1;

  float aL0 = 1.f, bL0 = 1.f, cL0 = 0.f, aL1 = 1.f, bL1 = 1.f, cL1 = 0.f;
#pragma unroll
  for (int i = 0; i < LSEG; ++i) {
    cL0 = fmaf(b0, cL0, ob0 * aL0); aL0 *= a0; bL0 *= b0;
    cL1 = fmaf(b1, cL1, ob1 * aL1); aL1 *= a1; bL1 *= b1;
  }

  float S0 = 0.f, M0 = 0.f, S1 = 0.f, M1 = 0.f;
  for (int j = 0; j < seg; ++j) {
    const float4 E = *(const float4*)&ep[(size_t)j * BO + b * On + o];
    const float nS0 = fmaf(aL0, S0, E.x);
    M0 = fmaf(bL0, M0, fmaf(cL0, S0, E.y));   // uses OLD S
    S0 = nS0;
    const float nS1 = fmaf(aL1, S1, E.z);
    M1 = fmaf(bL1, M1, fmaf(cL1, S1, E.w));
    S1 = nS1;
  }

  const ushort* hp = Hb + ((size_t)b * Tn + seg * LSEG) * On + o;
  float* sp = syn + ((size_t)b * Tn + seg * LSEG) * On + o;
  float* mp = mem + ((size_t)b * Tn + seg * LSEG) * On + o;
  uint32_t buf[8];
#pragma unroll
  for (int d = 0; d < 8; ++d) buf[d] = *(const uint32_t*)&hp[d * On];
  for (int tb = 0; tb < LSEG; tb += 8) {
#pragma unroll
    for (int d = 0; d < 8; ++d) {
      const int t = tb + d;
      const uint32_t u = buf[d];
      if (t + 8 < LSEG) buf[d] = *(const uint32_t*)&hp[(t + 8) * On];
      *(float2*)&sp[(size_t)t * On] = make_float2(S0, S1);
      *(float2*)&mp[(size_t)t * On] = make_float2(M0, M1);
      const float x0 = bitsf(u << 16);
      const float x1 = bitsf(u & 0xFFFF0000u);
      M0 = fmaf(b0, M0, ob0 * S0); S0 = fmaf(a0, S0, x0);   // M uses OLD S
      M1 = fmaf(b1, M1, ob1 * S1); S1 = fmaf(a1, S1, x1);
    }
  }
}

// ---- Phase B+C, fp32-h fallback (h in syn region, in-place) ----
__global__ __launch_bounds__(256) void scan_seg(
    float* __restrict__ syn, float* __restrict__ mem, const float2* __restrict__ ep,
    const float* __restrict__ alpha, const float* __restrict__ beta)
{
  const int cid = blockIdx.x * 256 + threadIdx.x;
  const int o2  = cid & 63;
  const int seg = (cid >> 6) & (NSEG - 1);
  const int b   = cid >> 10;
  const int o   = 2 * o2;

  const float2 al2 = *(const float2*)&alpha[o];
  const float2 be2 = *(const float2*)&beta[o];
  const float a0 = al2.x, a1 = al2.y, b0 = be2.x, b1 = be2.y;
  const float ob0 = 1.f - b0, ob1 = 1.f - b1;

  float aL0 = 1.f, bL0 = 1.f, cL0 = 0.f, aL1 = 1.f, bL1 = 1.f, cL1 = 0.f;
#pragma unroll
  for (int i = 0; i < LSEG; ++i) {
    cL0 = fmaf(b0, cL0, ob0 * aL0); aL0 *= a0; bL0 *= b0;
    cL1 = fmaf(b1, cL1, ob1 * aL1); aL1 *= a1; bL1 *= b1;
  }

  float S0 = 0.f, M0 = 0.f, S1 = 0.f, M1 = 0.f;
  for (int j = 0; j < seg; ++j) {
    const float4 E = *(const float4*)&ep[(size_t)j * BO + b * On + o];
    const float nS0 = fmaf(aL0, S0, E.x);
    M0 = fmaf(bL0, M0, fmaf(cL0, S0, E.y));
    S0 = nS0;
    const float nS1 = fmaf(aL1, S1, E.z);
    M1 = fmaf(bL1, M1, fmaf(cL1, S1, E.w));
    S1 = nS1;
  }

  float* hp = syn + ((size_t)b * Tn + seg * LSEG) * On + o;
  float* mp = mem + ((size_t)b * Tn + seg * LSEG) * On + o;
  float2 buf[8];
#pragma unroll
  for (int d = 0; d < 8; ++d) buf[d] = *(const float2*)&hp[d * On];
  for (int tb = 0; tb < LSEG; tb += 8) {
#pragma unroll
    for (int d = 0; d < 8; ++d) {
      const int t = tb + d;
      const float2 x = buf[d];
      if (t + 8 < LSEG) buf[d] = *(const float2*)&hp[(t + 8) * On];
      *(float2*)&hp[(size_t)t * On] = make_float2(S0, S1);
      *(float2*)&mp[(size_t)t * On] = make_float2(M0, M1);
      M0 = fmaf(b0, M0, ob0 * S0); S0 = fmaf(a0, S0, x.x);
      M1 = fmaf(b1, M1, ob1 * S1); S1 = fmaf(a1, S1, x.y);
    }
  }
}

// ---- fallback single-pass scan (used only if ws_size is tiny) ----
__global__ __launch_bounds__(64) void scan_k(
    float* __restrict__ syn, float* __restrict__ mem,
    const float* __restrict__ alpha, const float* __restrict__ beta)
{
  const int b = blockIdx.x >> 1;
  const int o = ((blockIdx.x & 1) << 6) + threadIdx.x;
  const float a = alpha[o], bt = beta[o], omb = 1.0f - bt;
  float* hp = syn + (size_t)b * Tn * On + o;
  float* mp = mem + (size_t)b * Tn * On + o;
  float S = 0.f, M = 0.f;
  float buf[8];
#pragma unroll
  for (int d = 0; d < 8; ++d) buf[d] = hp[d * On];
  for (int tb = 0; tb < Tn; tb += 8) {
#pragma unroll
    for (int d = 0; d < 8; ++d) {
      const int t = tb + d;
      const float h_t = buf[d];
      if (t + 8 < Tn) buf[d] = hp[(t + 8) * On];
      hp[t * On] = S;
      mp[t * On] = M;
      const float nS = fmaf(a, S, h_t);
      M = fmaf(bt, M, omb * S);
      S = nS;
    }
  }
}

extern "C" void kernel_launch(void* const* d_in, const int* in_sizes, int n_in,
                              void* d_out, int out_size, void* d_ws, size_t ws_size,
                              hipStream_t stream) {
  const float* inputs = (const float*)d_in[0];   // (128,512,700)
  const float* w      = (const float*)d_in[1];   // (700,128)
  const float* alpha  = (const float*)d_in[2];   // (1,128)
  const float* beta   = (const float*)d_in[3];   // (1,128)

  float* syn = (float*)d_out;                    // first 8M floats
  float* mem = syn + (size_t)Bsz * Tn * On;      // next 8M floats
  ushort* w_t = (ushort*)mem;                    // 180 KB temp in mem region,
                                                 // consumed by gemm before scan writes

  const size_t ep_bytes = (size_t)NSEG * BO * sizeof(float2);  // 2 MB
  const size_t hb_bytes = (size_t)Mn * On * sizeof(ushort);    // 16.78 MB

  prep_wt<<<(On * KP + 255) / 256, 256, 0, stream>>>(w, w_t);

  if (ws_size >= ep_bytes + hb_bytes) {
    float2* ep = (float2*)d_ws;
    ushort* hb = (ushort*)((char*)d_ws + ep_bytes);
    gemm_hb<<<Mn / 128, 256, 0, stream>>>(inputs, w_t, hb, ep, alpha, beta);
    scan_segb<<<(Bsz * NSEG * On / 2) / 256, 256, 0, stream>>>(syn, mem, hb, ep, alpha, beta);
  } else if (ws_size >= ep_bytes) {
    float2* ep = (float2*)d_ws;
    gemm_h<<<Mn / 128, 256, 0, stream>>>(inputs, w_t, syn, ep, alpha, beta);
    scan_seg<<<(Bsz * NSEG * On / 2) / 256, 256, 0, stream>>>(syn, mem, ep, alpha, beta);
  } else {
    gemm_h<<<Mn / 128, 256, 0, stream>>>(inputs, w_t, syn, nullptr, alpha, beta);
    scan_k<<<Bsz * 2, 64, 0, stream>>>(syn, mem, alpha, beta);
  }
}

// Round 10
// 63.159 us; speedup vs baseline: 1.6091x; 1.0452x over previous
//
#include <hip/hip_runtime.h>
#include <hip/hip_bf16.h>
#include <stdint.h>

#define Bsz 128
#define Tn  512
#define In  700
#define On  128
#define Mn  (Bsz * Tn)   // 65536
#define KP  704          // K padded to multiple of 32
#define NSEG 16
#define LSEG 32          // Tn / NSEG
#define BO   (Bsz * On)  // 16384 chains
#define NKT  22          // K tiles of 32
#define SCP  136         // ushort sc row pitch (272B, 16B-aligned)

using bf16x8 = __attribute__((ext_vector_type(8))) short;
using f32x4  = __attribute__((ext_vector_type(4))) float;

#define WAITVM(N) asm volatile("s_waitcnt vmcnt(" #N ")" ::: "memory")

__device__ __forceinline__ uint32_t f2bf(float f) {
  union { float f; uint32_t u; } v; v.f = f;
  return (v.u + 0x7fffu + ((v.u >> 16) & 1u)) >> 16;   // RNE
}
__device__ __forceinline__ float bf2f(ushort u) {
  union { float f; uint32_t x; } v; v.x = ((uint32_t)u) << 16;
  return v.f;
}
__device__ __forceinline__ float bitsf(uint32_t u) {
  union { float f; uint32_t x; } v; v.x = u; return v.f;
}

// pairwise f32->bf16 via v_cvt_pk_bf16_f32 (compiler-generated, RNE)
__device__ __forceinline__ bf16x8 cvt8(float4 f0, float4 f1) {
  union { __hip_bfloat162 h2[4]; bf16x8 v; } u;
  u.h2[0] = __float22bfloat162_rn(make_float2(f0.x, f0.y));
  u.h2[1] = __float22bfloat162_rn(make_float2(f0.z, f0.w));
  u.h2[2] = __float22bfloat162_rn(make_float2(f1.x, f1.y));
  u.h2[3] = __float22bfloat162_rn(make_float2(f1.z, f1.w));
  return u.v;
}

// async global->LDS, 16B per lane; LDS dest = wave-uniform base + lane*16
__device__ __forceinline__ void gload16(const void* g, void* l) {
  __builtin_amdgcn_global_load_lds(
      (__attribute__((address_space(1))) void*)g,
      (__attribute__((address_space(3))) void*)l, 16, 0, 0);
}

// ---- prep: w (700x128 f32, k-major) -> w_t (128 x 704 bf16, zero-padded K) ----
__global__ void prep_wt(const float* __restrict__ w, ushort* __restrict__ w_t) {
  int idx = blockIdx.x * 256 + threadIdx.x;
  if (idx >= On * KP) return;
  int col = idx / KP, k = idx - col * KP;
  float v = (k < In) ? w[(size_t)k * On + col] : 0.0f;
  w_t[(size_t)col * KP + k] = (ushort)f2bf(v);
}

// ========== GEMM, round-6 3-deep counted-vmcnt structure, bf16-h output ==========
union SMU {
  struct {
    uint32_t A[3][4096];   // 48 KB: fp32 tile 128 rows x 8 slots x 16B, src-swizzled
    uint32_t B[3][2048];   // 24 KB: bf16 tile 128 cols x 4 slots x 16B, src-swizzled
  } db;                    // 72 KB staging -> 2 blocks/CU
  ushort sc[128 * SCP];    // 34.8 KB h buffer (bf16 bits, t-major)
  float  scf[128 * 132];   // 66 KB fp32 h buffer (fallback path)
};

template <bool HB16>
__global__ __launch_bounds__(256, 2) void gemm_h(
    const float* __restrict__ A,    // 65536 x 700 f32
    const ushort* __restrict__ Wt,  // 128 x 704 bf16
    float* __restrict__ Hf,         // fp32 h out (syn region)  [!HB16]
    ushort* __restrict__ Hb,        // bf16 h out (d_ws)        [HB16]
    float2* __restrict__ ep,        // [NSEG][BO] endpoints (may be null)
    const float* __restrict__ alpha, const float* __restrict__ beta)
{
  __shared__ __align__(16) SMU sm;

  const int tid  = threadIdx.x;
  const int bm   = blockIdx.x;        // 512 blocks: batch b = bm>>2, quarter = bm&3
  const int lane = tid & 63;
  const int wid  = tid >> 6;          // 4 waves, 2x2 wave grid (64x64 each)
  const int wm   = wid >> 1, wn = wid & 1;
  const int l16  = lane & 15, lkb = lane >> 4;

  // alpha/beta for phase A; drain so the counted vmcnt pipeline stays exact
  const int   o_ep = tid & 127;
  const float a_ep = alpha[o_ep];
  const float b_ep = beta[o_ep];
  WAITVM(0);
  __builtin_amdgcn_sched_barrier(0);

  f32x4 acc[4][4];
#pragma unroll
  for (int i = 0; i < 4; ++i)
#pragma unroll
    for (int n = 0; n < 4; ++n) acc[i][n] = (f32x4){0.f, 0.f, 0.f, 0.f};

  auto stage = [&](int bi, int kt) {   // 6 loads per wave
    const int k0 = kt * 32;
#pragma unroll
    for (int is = 0; is < 4; ++is) {
      const int q   = is * 256 + wid * 64 + lane;
      const int row = q >> 3, sl = q & 7;
      int gk = k0 + ((sl ^ (row & 7)) << 2);
      if (gk >= In) gk = k0;                        // clamp; Wt zero at k>=700
      gload16(A + (size_t)(bm * 128 + row) * In + gk,
              &sm.db.A[bi][is * 1024 + wid * 256]);
    }
#pragma unroll
    for (int is = 0; is < 2; ++is) {
      const int q   = is * 256 + wid * 64 + lane;
      const int col = q >> 2, sl = q & 3;
      const int ks  = sl ^ ((col >> 1) & 3);
      gload16(Wt + (size_t)col * KP + k0 + ks * 8,
              &sm.db.B[bi][is * 1024 + wid * 256]);
    }
  };

  auto tile = [&](int kt, int cur) {
    __builtin_amdgcn_s_barrier();
    const float4* Af = (const float4*)sm.db.A[cur];
    const bf16x8* Bf = (const bf16x8*)sm.db.B[cur];
    bf16x8 af[4], bfr[4];
#pragma unroll
    for (int i = 0; i < 4; ++i) {
      const int row = wm * 64 + i * 16 + l16;
      const int s0  = (lkb * 2) ^ (row & 7);
      const int s1  = (lkb * 2 + 1) ^ (row & 7);
      af[i] = cvt8(Af[row * 8 + s0], Af[row * 8 + s1]);
    }
#pragma unroll
    for (int n = 0; n < 4; ++n) {
      const int col = wn * 64 + n * 16 + l16;
      bfr[n] = Bf[col * 4 + (lkb ^ ((col >> 1) & 3))];
    }
    asm volatile("s_waitcnt lgkmcnt(0)" ::: "memory");
    __builtin_amdgcn_s_barrier();
    if (kt + 3 < NKT) stage(cur, kt + 3);   // overwrite just-consumed buffer
#pragma unroll
    for (int i = 0; i < 4; ++i)
#pragma unroll
      for (int n = 0; n < 4; ++n)
        acc[i][n] = __builtin_amdgcn_mfma_f32_16x16x32_bf16(af[i], bfr[n], acc[i][n], 0, 0, 0);
  };

  stage(0, 0); stage(1, 1); stage(2, 2);    // 18 loads/wave in flight
  {
    int cur = 0;
    for (int kt = 0; kt < NKT - 2; ++kt) {  // kt = 0..19: 3 tiles outstanding
      WAITVM(12);
      tile(kt, cur);
      cur = (cur == 2) ? 0 : cur + 1;
    }
    WAITVM(6);  tile(NKT - 2, (NKT - 2) % 3);
    WAITVM(0);  tile(NKT - 1, (NKT - 1) % 3);
  }

  if constexpr (HB16) {
    // ---- epilogue: acc -> bf16 bits in LDS (t-major, pitch 136) ----
#pragma unroll
    for (int i = 0; i < 4; ++i)
#pragma unroll
      for (int n = 0; n < 4; ++n) {
        const int col = wn * 64 + n * 16 + l16;
#pragma unroll
        for (int r = 0; r < 4; ++r) {
          const int row = wm * 64 + i * 16 + lkb * 4 + r;
          sm.sc[row * SCP + col] = (ushort)f2bf(acc[i][n][r]);
        }
      }
    __syncthreads();

    // coalesced h write: 16B (8 bf16) per thread per pass
#pragma unroll
    for (int i2 = 0; i2 < 8; ++i2) {
      const int q = i2 * 256 + tid;
      const int row = q >> 4, v8 = q & 15;
      *(uint4*)&Hb[(size_t)(bm * 128 + row) * 128 + v8 * 8] =
          *(const uint4*)&sm.sc[row * SCP + v8 * 8];
    }

    // fused phase A: per-segment local scan from zero on bf16-exact values
    {
      const float a = a_ep, bt = b_ep, omb = 1.0f - b_ep;
      const int b = bm >> 2, seg0 = (bm & 3) * 4;
#pragma unroll
      for (int cc = 0; cc < 2; ++cc) {
        const int sl = (tid >> 7) + cc * 2;
        float S = 0.f, M = 0.f;
        const ushort* base = &sm.sc[(sl * 32) * SCP + o_ep];
#pragma unroll
        for (int t = 0; t < 32; ++t) {
          const float x = bf2f(base[t * SCP]);
          M = fmaf(bt, M, omb * S);   // uses OLD S
          S = fmaf(a, S, x);
        }
        ep[(size_t)(seg0 + sl) * BO + b * On + o_ep] = make_float2(S, M);
      }
    }
  } else {
    // ---- fp32 epilogue (fallback path) ----
#pragma unroll
    for (int i = 0; i < 4; ++i)
#pragma unroll
      for (int n = 0; n < 4; ++n) {
        const int col = wn * 64 + n * 16 + l16;
#pragma unroll
        for (int r = 0; r < 4; ++r) {
          const int row = wm * 64 + i * 16 + lkb * 4 + r;
          sm.scf[row * 132 + col] = acc[i][n][r];
        }
      }
    __syncthreads();

    const size_t hbase = (size_t)bm * 128 * 128;
#pragma unroll
    for (int i2 = 0; i2 < 16; ++i2) {
      const int q = i2 * 256 + tid;
      const int row = q >> 5, v = q & 31;
      *(float4*)&Hf[hbase + row * 128 + v * 4] =
          *(const float4*)&sm.scf[row * 132 + v * 4];
    }

    if (ep) {
      const float a = a_ep, bt = b_ep, omb = 1.0f - b_ep;
      const int b = bm >> 2, seg0 = (bm & 3) * 4;
#pragma unroll
      for (int cc = 0; cc < 2; ++cc) {
        const int sl = (tid >> 7) + cc * 2;
        float S = 0.f, M = 0.f;
        const float* base = &sm.scf[(sl * 32) * 132 + o_ep];
#pragma unroll
        for (int t = 0; t < 32; ++t) {
          const float x = base[t * 132];
          M = fmaf(bt, M, omb * S);
          S = fmaf(a, S, x);
        }
        ep[(size_t)(seg0 + sl) * BO + b * On + o_ep] = make_float2(S, M);
      }
    }
  }
}

// ---- Phase B+C, bf16-h, 2 o's per thread (512 blocks) ----
__global__ __launch_bounds__(256) void scan_segb(
    float* __restrict__ syn, float* __restrict__ mem,
    const ushort* __restrict__ Hb, const float2* __restrict__ ep,
    const float* __restrict__ alpha, const float* __restrict__ beta)
{
  const int cid = blockIdx.x * 256 + threadIdx.x;   // 128*16*64 = 131072
  const int o2  = cid & 63;
  const int seg = (cid >> 6) & (NSEG - 1);
  const int b   = cid >> 10;
  const int o   = 2 * o2;

  const float2 al2 = *(const float2*)&alpha[o];
  const float2 be2 = *(const float2*)&beta[o];
  const float a0 = al2.x, a1 = al2.y, b0 = be2.x, b1 = be2.y;
  const float ob0 = 1.f - b0, ob1 = 1.f - b1;

  float aL0 = 1.f, bL0 = 1.f, cL0 = 0.f, aL1 = 1.f, bL1 = 1.f, cL1 = 0.f;
#pragma unroll
  for (int i = 0; i < LSEG; ++i) {
    cL0 = fmaf(b0, cL0, ob0 * aL0); aL0 *= a0; bL0 *= b0;
    cL1 = fmaf(b1, cL1, ob1 * aL1); aL1 *= a1; bL1 *= b1;
  }

  float S0 = 0.f, M0 = 0.f, S1 = 0.f, M1 = 0.f;
  for (int j = 0; j < seg; ++j) {
    const float4 E = *(const float4*)&ep[(size_t)j * BO + b * On + o];
    const float nS0 = fmaf(aL0, S0, E.x);
    M0 = fmaf(bL0, M0, fmaf(cL0, S0, E.y));   // uses OLD S
    S0 = nS0;
    const float nS1 = fmaf(aL1, S1, E.z);
    M1 = fmaf(bL1, M1, fmaf(cL1, S1, E.w));
    S1 = nS1;
  }

  const ushort* hp = Hb + ((size_t)b * Tn + seg * LSEG) * On + o;
  float* sp = syn + ((size_t)b * Tn + seg * LSEG) * On + o;
  float* mp = mem + ((size_t)b * Tn + seg * LSEG) * On + o;
  uint32_t buf[8];
#pragma unroll
  for (int d = 0; d < 8; ++d) buf[d] = *(const uint32_t*)&hp[d * On];
  for (int tb = 0; tb < LSEG; tb += 8) {
#pragma unroll
    for (int d = 0; d < 8; ++d) {
      const int t = tb + d;
      const uint32_t u = buf[d];
      if (t + 8 < LSEG) buf[d] = *(const uint32_t*)&hp[(t + 8) * On];
      *(float2*)&sp[(size_t)t * On] = make_float2(S0, S1);
      *(float2*)&mp[(size_t)t * On] = make_float2(M0, M1);
      const float x0 = bitsf(u << 16);
      const float x1 = bitsf(u & 0xFFFF0000u);
      M0 = fmaf(b0, M0, ob0 * S0); S0 = fmaf(a0, S0, x0);   // M uses OLD S
      M1 = fmaf(b1, M1, ob1 * S1); S1 = fmaf(a1, S1, x1);
    }
  }
}

// ---- Phase B+C, fp32-h fallback (h in syn region, in-place) ----
__global__ __launch_bounds__(256) void scan_seg(
    float* __restrict__ syn, float* __restrict__ mem, const float2* __restrict__ ep,
    const float* __restrict__ alpha, const float* __restrict__ beta)
{
  const int cid = blockIdx.x * 256 + threadIdx.x;
  const int o2  = cid & 63;
  const int seg = (cid >> 6) & (NSEG - 1);
  const int b   = cid >> 10;
  const int o   = 2 * o2;

  const float2 al2 = *(const float2*)&alpha[o];
  const float2 be2 = *(const float2*)&beta[o];
  const float a0 = al2.x, a1 = al2.y, b0 = be2.x, b1 = be2.y;
  const float ob0 = 1.f - b0, ob1 = 1.f - b1;

  float aL0 = 1.f, bL0 = 1.f, cL0 = 0.f, aL1 = 1.f, bL1 = 1.f, cL1 = 0.f;
#pragma unroll
  for (int i = 0; i < LSEG; ++i) {
    cL0 = fmaf(b0, cL0, ob0 * aL0); aL0 *= a0; bL0 *= b0;
    cL1 = fmaf(b1, cL1, ob1 * aL1); aL1 *= a1; bL1 *= b1;
  }

  float S0 = 0.f, M0 = 0.f, S1 = 0.f, M1 = 0.f;
  for (int j = 0; j < seg; ++j) {
    const float4 E = *(const float4*)&ep[(size_t)j * BO + b * On + o];
    const float nS0 = fmaf(aL0, S0, E.x);
    M0 = fmaf(bL0, M0, fmaf(cL0, S0, E.y));
    S0 = nS0;
    const float nS1 = fmaf(aL1, S1, E.z);
    M1 = fmaf(bL1, M1, fmaf(cL1, S1, E.w));
    S1 = nS1;
  }

  float* hp = syn + ((size_t)b * Tn + seg * LSEG) * On + o;
  float* mp = mem + ((size_t)b * Tn + seg * LSEG) * On + o;
  float2 buf[8];
#pragma unroll
  for (int d = 0; d < 8; ++d) buf[d] = *(const float2*)&hp[d * On];
  for (int tb = 0; tb < LSEG; tb += 8) {
#pragma unroll
    for (int d = 0; d < 8; ++d) {
      const int t = tb + d;
      const float2 x = buf[d];
      if (t + 8 < LSEG) buf[d] = *(const float2*)&hp[(t + 8) * On];
      *(float2*)&hp[(size_t)t * On] = make_float2(S0, S1);
      *(float2*)&mp[(size_t)t * On] = make_float2(M0, M1);
      M0 = fmaf(b0, M0, ob0 * S0); S0 = fmaf(a0, S0, x.x);
      M1 = fmaf(b1, M1, ob1 * S1); S1 = fmaf(a1, S1, x.y);
    }
  }
}

// ---- fallback single-pass scan (used only if ws_size is tiny) ----
__global__ __launch_bounds__(64) void scan_k(
    float* __restrict__ syn, float* __restrict__ mem,
    const float* __restrict__ alpha, const float* __restrict__ beta)
{
  const int b = blockIdx.x >> 1;
  const int o = ((blockIdx.x & 1) << 6) + threadIdx.x;
  const float a = alpha[o], bt = beta[o], omb = 1.0f - bt;
  float* hp = syn + (size_t)b * Tn * On + o;
  float* mp = mem + (size_t)b * Tn * On + o;
  float S = 0.f, M = 0.f;
  float buf[8];
#pragma unroll
  for (int d = 0; d < 8; ++d) buf[d] = hp[d * On];
  for (int tb = 0; tb < Tn; tb += 8) {
#pragma unroll
    for (int d = 0; d < 8; ++d) {
      const int t = tb + d;
      const float h_t = buf[d];
      if (t + 8 < Tn) buf[d] = hp[(t + 8) * On];
      hp[t * On] = S;
      mp[t * On] = M;
      const float nS = fmaf(a, S, h_t);
      M = fmaf(bt, M, omb * S);
      S = nS;
    }
  }
}

extern "C" void kernel_launch(void* const* d_in, const int* in_sizes, int n_in,
                              void* d_out, int out_size, void* d_ws, size_t ws_size,
                              hipStream_t stream) {
  const float* inputs = (const float*)d_in[0];   // (128,512,700)
  const float* w      = (const float*)d_in[1];   // (700,128)
  const float* alpha  = (const float*)d_in[2];   // (1,128)
  const float* beta   = (const float*)d_in[3];   // (1,128)

  float* syn = (float*)d_out;                    // first 8M floats
  float* mem = syn + (size_t)Bsz * Tn * On;      // next 8M floats
  ushort* w_t = (ushort*)mem;                    // 180 KB temp in mem region,
                                                 // consumed by gemm before scan writes

  const size_t ep_bytes = (size_t)NSEG * BO * sizeof(float2);  // 2 MB
  const size_t hb_bytes = (size_t)Mn * On * sizeof(ushort);    // 16.78 MB

  prep_wt<<<(On * KP + 255) / 256, 256, 0, stream>>>(w, w_t);

  if (ws_size >= ep_bytes + hb_bytes) {
    float2* ep = (float2*)d_ws;
    ushort* hb = (ushort*)((char*)d_ws + ep_bytes);
    gemm_h<true><<<Mn / 128, 256, 0, stream>>>(inputs, w_t, nullptr, hb, ep, alpha, beta);
    scan_segb<<<(Bsz * NSEG * On / 2) / 256, 256, 0, stream>>>(syn, mem, hb, ep, alpha, beta);
  } else if (ws_size >= ep_bytes) {
    float2* ep = (float2*)d_ws;
    gemm_h<false><<<Mn / 128, 256, 0, stream>>>(inputs, w_t, syn, nullptr, ep, alpha, beta);
    scan_seg<<<(Bsz * NSEG * On / 2) / 256, 256, 0, stream>>>(syn, mem, ep, alpha, beta);
  } else {
    gemm_h<false><<<Mn / 128, 256, 0, stream>>>(inputs, w_t, syn, nullptr, nullptr, alpha, beta);
    scan_k<<<Bsz * 2, 64, 0, stream>>>(syn, mem, alpha, beta);
  }
}